// Round 20
// baseline (42.891 us; speedup 1.0000x reference)
//
#include <hip/hip_runtime.h>
#include <math.h>

// Problem constants (fixed by the reference)
#define B_    16
#define F_    32
#define NP_   128   // rows per (b,f) panel
#define D_    512
#define P_    16
#define NSL   16            // total slab-steps (2 panels x 8 slabs of 16 rows)
#define SLABF 4096          // float-units per slab LDS image (16 KB bf16)
#define E0OFF (4 * SLABF)   // ring = 4 slabs = 64 KB
#define E1OFF (E0OFF + NP_ * 33)

typedef __attribute__((ext_vector_type(8))) short  short8;   // 8 bf16
typedef __attribute__((ext_vector_type(4))) float  floatx4;  // 16x16 acc

union Frag { short8 v; unsigned int u[4]; };

__device__ inline unsigned int cvt_pk_bf16(float lo, float hi) {
    unsigned int r;
    asm volatile("v_cvt_pk_bf16_f32 %0, %1, %2" : "=v"(r) : "v"(lo), "v"(hi));
    return r;
}

#define SB  __builtin_amdgcn_sched_barrier(0)
#define BAR asm volatile("s_waitcnt lgkmcnt(0)\n\ts_barrier" ::: "memory")

// 256 blocks (1/CU) x 1024 threads = 16 waves (4/SIMD — R20: doubled wave-
// level memory parallelism; every streaming round so far ran 2/SIMD).
// R19 slab structure kept: slab = 16 complete rows (32 KB contiguous);
// wave pair mt=wave>>1 owns slabs g==mt (mod 8) and computes the full
// 16-k-step GEMM (16x16x32, no K-split, bias/exp fused into C-write).
// Reg-staging: each thread 2x float4 -> 1 swizzled ds_write_b128 per step.
// Ring of 4 slab images, loads 3 steps ahead, ONE barrier per step;
// panel-0 gather folded into steps 9-12; 2 adjacent panels per block.
__global__ __launch_bounds__(1024, 4)
void pd_kernel(const float* __restrict__ ts,
               const float* __restrict__ W,
               const float* __restrict__ bias,
               float* __restrict__ out, int T)
{
    __shared__ float smem[E1OFF + NP_ * 33];   // 64 KB ring + 2 E buffers

    const int tid  = threadIdx.x;
    const int lane = tid & 63;
    const int wave = tid >> 6;       // 0..15
    const int nt   = wave & 1;       // e-half: e in [16nt, 16nt+16)
    const int mt   = wave >> 1;      // slab owner: slabs g with (g&7)==mt

    // 256-block XCD encoding (proven): panels are adjacent f's of one b
    const int d  = blockIdx.x;
    const int b  = (d & 7) | (((d >> 7) & 1) << 3);
    const int fp = (d >> 3) & 15;
    const float* __restrict__ tsb0 = ts + ((size_t)(b * F_ + 2 * fp) * NP_) * D_;
    const float* __restrict__ tsb1 = tsb0 + (size_t)NP_ * D_;

    // slab staging: thread -> row lr (0..15), 8-float span lq (0..63).
    // Consecutive threads read consecutive 32B; whole 32 KB slab contiguous.
    const int lr = tid >> 6;
    const int lq = tid & 63;

    float4 st[3][2];                 // staged regs, 3 slab-steps deep
    auto LOAD = [&](int g) {
        const float* src = (g < 8 ? tsb0 : tsb1)
                         + ((size_t)((g & 7) * 16 + lr)) * D_ + lq * 8;
        st[g % 3][0] = ((const float4*)src)[0];
        st[g % 3][1] = ((const float4*)src)[1];
    };
    // cvt 8 fp32 -> 8 bf16 -> ONE swizzled b128 quad into slab image g&3.
    // Slab image: [16 rows][64 quads]; quad q of row r stored at q^r
    // (bijective; read side uses the same XOR -> conflict-free, R19-proven).
    auto WRITE = [&](int g) {
        Frag q;
        q.u[0] = cvt_pk_bf16(st[g%3][0].x, st[g%3][0].y);
        q.u[1] = cvt_pk_bf16(st[g%3][0].z, st[g%3][0].w);
        q.u[2] = cvt_pk_bf16(st[g%3][1].x, st[g%3][1].y);
        q.u[3] = cvt_pk_bf16(st[g%3][1].z, st[g%3][1].w);
        short8* slab = (short8*)(smem + (g & 3) * SLABF);
        slab[lr * 64 + (lq ^ lr)] = q.v;
    };

    // ---- prologue: stream first, B preload overlapped
    LOAD(0); SB;
    LOAD(1); LOAD(2); SB;

    // B preload: e = nt*16 + (lane&15); k-half kg = lane>>4; 16 k-steps.
    const int el = lane & 15;
    const int kg = lane >> 4;
    const int ef = nt * 16 + el;
    Frag bf[16];
    {
        const float* wb = W + (size_t)ef * D_ + kg * 8;
#pragma unroll
        for (int ks = 0; ks < 16; ++ks) {
            const float4 lo = *(const float4*)(wb + ks * 32);
            const float4 hi = *(const float4*)(wb + ks * 32 + 4);
            bf[ks].u[0] = cvt_pk_bf16(lo.x, lo.y);
            bf[ks].u[1] = cvt_pk_bf16(lo.z, lo.w);
            bf[ks].u[2] = cvt_pk_bf16(hi.x, hi.y);
            bf[ks].u[3] = cvt_pk_bf16(hi.z, hi.w);
        }
    }
    SB;
    WRITE(0);
    BAR; SB;

    const int TF = T * F_;
    const size_t halfoff = (size_t)B_ * TF;
    const int f0 = 2 * fp, f1 = 2 * fp + 1;
    const int QT = (2 * T + 3) / 4;

    auto GATHER = [&](const float* E, int f, int lo_i, int hi_i) {
        for (int item = lo_i + tid; item < hi_i; item += 1024) {
            const int half = (item >= T) ? 1 : 0;
            const int t    = item - half * T;
            const int nmax = min(NP_ - 1, t >> 3);
            const int nmin = (t > 8) ? ((t - 8) >> 3) : 0;
            float sum = 0.f;
            const int cnt = nmax - nmin + 1;
            for (int nn = nmin; nn <= nmax; ++nn)
                sum += E[nn * 33 + (half << 4) + (t - (nn << 3))];
            const float r = (cnt > 0) ? sum / (float)cnt : 0.f;
            out[(size_t)half * halfoff + (size_t)b * TF + (size_t)t * F_ + f] = r;
        }
    };

    // ---- 16 slab-steps, one barrier each
#pragma unroll
    for (int g = 0; g < NSL; ++g) {
        if (g + 1 < NSL) WRITE(g + 1);   // slot (g+1)&3: last read slab g-3
        if (g + 3 < NSL) LOAD(g + 3);    // 3 steps of load slack
        SB;
        BAR;                              // publishes slab g+1; slab g ready
        SB;

        if (g >= 9 && g <= 12) {          // panel-0 gather quarters
            const int gq = g - 9;
            GATHER(smem + E0OFF, f0, gq * QT, min((gq + 1) * QT, 2 * T));
        }

        if ((g & 7) == mt) {              // this wave pair owns slab g
            const short8* slab = (const short8*)(smem + (g & 3) * SLABF);
            floatx4 a4;
#pragma unroll
            for (int r = 0; r < 4; ++r) a4[r] = 0.f;
#pragma unroll
            for (int ks = 0; ks < 16; ++ks) {
                Frag a;
                a.v = slab[el * 64 + ((ks * 4 + kg) ^ el)];
                a4 = __builtin_amdgcn_mfma_f32_16x16x32_bf16(a.v, bf[ks].v, a4, 0, 0, 0);
            }
            // C-tile FINAL (no K-split): fused bias/exp, direct E write.
            // 16x16 C map (R12-verified): col=lane&15, row=kg*4+r.
            float* E = smem + (g < 8 ? E0OFF : E1OFF);
            const float bv = bias[ef];
#pragma unroll
            for (int r = 0; r < 4; ++r) {
                const int rowl = (g & 7) * 16 + kg * 4 + r;
                float v = a4[r] + bv;
                if (ef >= P_) v = fmaxf(expf(v), 1e-6f);   // wave-uniform
                E[rowl * 33 + ef] = v;
            }
        }
    }

    // ---- tail: panel-1 gather
    BAR;
    GATHER(smem + E1OFF, f1, 0, 2 * T);
}

extern "C" void kernel_launch(void* const* d_in, const int* in_sizes, int n_in,
                              void* d_out, int out_size, void* d_ws, size_t ws_size,
                              hipStream_t stream)
{
    const float* ts   = (const float*)d_in[0];
    const float* W    = (const float*)d_in[1];
    const float* bias = (const float*)d_in[2];
    float* out = (float*)d_out;

    // T derived on host from out_size = 2 * B * T * F
    const int T = out_size / (2 * B_ * F_);

    dim3 grid(B_ * F_ / 2);   // 256 blocks: 1 per CU, 2 adjacent panels each
    dim3 block(1024);
    pd_kernel<<<grid, block, 0, stream>>>(ts, W, bias, out, T);
}